// Round 10
// baseline (1974.853 us; speedup 1.0000x reference)
//
#include <hip/hip_runtime.h>
#include <hip/hip_bf16.h>
#include <cmath>
#include <cstdint>

#define B_  2
#define T_  1024
#define V_  32000
#define D_  1024
#define H_  16
#define L_  8
#define DH_ 64

typedef __attribute__((ext_vector_type(8))) short bf16x8;
typedef __attribute__((ext_vector_type(4))) float f32x4;

__device__ __forceinline__ ushort f2bf(float f) {
    union { float f; uint32_t u; } v; v.f = f;
    uint32_t r = v.u + 0x7FFFu + ((v.u >> 16) & 1u);
    return (ushort)(r >> 16);
}
__device__ __forceinline__ float bf2f(ushort u) {
    union { uint32_t u; float f; } v; v.u = ((uint32_t)u) << 16;
    return v.f;
}

__device__ __forceinline__ void async_copy16(const void* g, void* l) {
    __builtin_amdgcn_global_load_lds(
        (const __attribute__((address_space(1))) void*)g,
        (__attribute__((address_space(3))) void*)l, 16, 0, 0);
}

// ---------------- fp32 -> bf16 cast (weights) ----------------
__global__ __launch_bounds__(256) void k_cast(const float4* __restrict__ in,
                                              ushort4* __restrict__ out, int n4) {
    for (int i = blockIdx.x * 256 + threadIdx.x; i < n4; i += gridDim.x * 256) {
        float4 v = in[i];
        out[i] = make_ushort4(f2bf(v.x), f2bf(v.y), f2bf(v.z), f2bf(v.w));
    }
}

// ---------------- RoPE tables: cos/sin (T, 32) ----------------
__global__ void k_rope_tables(float* __restrict__ cosT, float* __restrict__ sinT) {
    int t = blockIdx.x;
    int i = threadIdx.x;           // 0..31
    float invf = (i < 16) ? powf(1000.0f, -(float)i / 16.0f) : 0.0f;
    float th = (float)t * invf;
    cosT[t * 32 + i] = cosf(th);
    sinT[t * 32 + i] = sinf(th);
}

// ---------------- Embedding gather: fp32 x, bf16 mirror, row sum-of-squares ----------------
__global__ __launch_bounds__(256) void k_gather(const int* __restrict__ idx,
                                                const float* __restrict__ emb,
                                                float* __restrict__ x,
                                                ushort* __restrict__ xb,
                                                float* __restrict__ ss) {
    int row = blockIdx.x;
    int id = idx[row];
    float4 v = ((const float4*)(emb + (size_t)id * D_))[threadIdx.x];
    ((float4*)(x + (size_t)row * D_))[threadIdx.x] = v;
    *(ushort4*)(xb + (size_t)row * D_ + threadIdx.x * 4) =
        make_ushort4(f2bf(v.x), f2bf(v.y), f2bf(v.z), f2bf(v.w));
    float s = v.x * v.x + v.y * v.y + v.z * v.z + v.w * v.w;
    #pragma unroll
    for (int off = 1; off < 64; off <<= 1) s += __shfl_xor(s, off);
    __shared__ float wsum[4];
    int lane = threadIdx.x & 63, wv = threadIdx.x >> 6;
    if (lane == 0) wsum[wv] = s;
    __syncthreads();
    if (threadIdx.x == 0) ss[row] = wsum[0] + wsum[1] + wsum[2] + wsum[3];
}

// ---------------- MFMA GEMM: C[m,n] = epi( sc[m] * sum_k A[m,k]*W[n,k] ) ----------------
// BM=128, BK=64, XOR-swizzled LDS (T2), XCD swizzle (T1).
// BN<=128: prefetch double-buffer. BN=256: single buffer, high-intensity tile.
// EPI: 0 none(+nontemporal), 1 +Res(fp32), 2 relu^2, 3 RoPE(qkv).
// RSCALE: scale rows by rsqrt(ssIn[row]/D+eps) (fused RMSNorm).
// SSOUT (EPI==1 only): write bf16 mirror xbOut and atomicAdd row sum-of-squares to ssOut.
template<int BN, int EPI, bool OUTBF, bool CONVB, bool RSCALE, bool SSOUT>
__global__ __launch_bounds__(256, 2) void k_mfma_gemm(const ushort* __restrict__ A,
                                                      const void* __restrict__ Wp,
                                                      void* __restrict__ Cp,
                                                      const float* __restrict__ Res,
                                                      const float* __restrict__ cosT,
                                                      const float* __restrict__ sinT,
                                                      const float* __restrict__ ssIn,
                                                      float* __restrict__ ssOut,
                                                      ushort* __restrict__ xbOut,
                                                      int M, int N, int K) {
    constexpr int BM = 128;
    constexpr int MI = 4;
    constexpr int NI = BN / 32;
    constexpr bool DBUF = (BN <= 128);
    constexpr int NB = DBUF ? 2 : 1;
    __shared__ ushort As[NB][BM][64];   // swizzled: chunk c of row r at byte ((c^(r&7))<<4)
    __shared__ ushort Bs[NB][BN][64];
    const int tid = threadIdx.x;
    const int wid = tid >> 6, lane = tid & 63;
    const int wr = wid >> 1, wc = wid & 1;
    const int r16 = lane & 15, kc = lane >> 4;
    const int rx = (r16 & 7) << 4;
    const int srow8 = tid >> 3;
    const int sdcp = tid & 7;

    // T1: XCD-aware block swizzle (valid when nwg % 8 == 0)
    const int nwg = gridDim.x * gridDim.y;
    int orig = blockIdx.y * gridDim.x + blockIdx.x;
    int swz = (nwg & 7) ? orig : ((orig & 7) * (nwg >> 3) + (orig >> 3));
    const size_t bm = (size_t)(swz % gridDim.x) * BM;
    const size_t bn = (size_t)(swz / gridDim.x) * BN;

    auto stage = [&](int buf, int k0) {
        #pragma unroll
        for (int i = 0; i < 4; i++) {
            const int row = i * 32 + srow8;
            const ushort* g = A + (bm + row) * (size_t)K + k0 + ((sdcp ^ (row & 7)) * 8);
            async_copy16(g, (char*)As + buf * (BM * 128) + (i * 256 + tid) * 16);
        }
        if constexpr (!CONVB) {
            const ushort* Wb = (const ushort*)Wp;
            #pragma unroll
            for (int i = 0; i < BN / 32; i++) {
                const int row = i * 32 + srow8;
                const ushort* g = Wb + (bn + row) * (size_t)K + k0 + ((sdcp ^ (row & 7)) * 8);
                async_copy16(g, (char*)Bs + buf * (BN * 128) + (i * 256 + tid) * 16);
            }
        } else {
            const float* Wf = (const float*)Wp;
            #pragma unroll
            for (int i = 0; i < BN / 32; i++) {
                const int row = i * 32 + srow8;
                const float* src = Wf + (bn + row) * (size_t)K + k0 + sdcp * 8;
                float4 v0 = *(const float4*)(src);
                float4 v1 = *(const float4*)(src + 4);
                union { ushort u[8]; bf16x8 v; } tmp;
                tmp.u[0] = f2bf(v0.x); tmp.u[1] = f2bf(v0.y);
                tmp.u[2] = f2bf(v0.z); tmp.u[3] = f2bf(v0.w);
                tmp.u[4] = f2bf(v1.x); tmp.u[5] = f2bf(v1.y);
                tmp.u[6] = f2bf(v1.z); tmp.u[7] = f2bf(v1.w);
                *(bf16x8*)((char*)Bs + buf * (BN * 128) + row * 128 + ((sdcp ^ (row & 7)) << 4)) = tmp.v;
            }
        }
    };

    f32x4 acc[MI][NI];
    #pragma unroll
    for (int mi = 0; mi < MI; mi++)
        #pragma unroll
        for (int ni = 0; ni < NI; ni++) {
            f32x4 z = {0.f, 0.f, 0.f, 0.f};
            acc[mi][ni] = z;
        }

    auto compute = [&](int buf) {
        #pragma unroll
        for (int kk = 0; kk < 2; kk++) {
            bf16x8 af[MI], bfr[NI];
            #pragma unroll
            for (int mi = 0; mi < MI; mi++)
                af[mi] = *(const bf16x8*)((const char*)As + buf * (BM * 128) +
                                          (wr * 64 + mi * 16 + r16) * 128 +
                                          ((kk * 64 + kc * 16) ^ rx));
            #pragma unroll
            for (int ni = 0; ni < NI; ni++)
                bfr[ni] = *(const bf16x8*)((const char*)Bs + buf * (BN * 128) +
                                           (wc * (BN / 2) + ni * 16 + r16) * 128 +
                                           ((kk * 64 + kc * 16) ^ rx));
            #pragma unroll
            for (int mi = 0; mi < MI; mi++)
                #pragma unroll
                for (int ni = 0; ni < NI; ni++)
                    acc[mi][ni] = __builtin_amdgcn_mfma_f32_16x16x32_bf16(af[mi], bfr[ni],
                                                                          acc[mi][ni], 0, 0, 0);
        }
    };

    const int KSTEPS = K >> 6;
    if constexpr (DBUF) {
        stage(0, 0);
        __syncthreads();
        for (int step = 0; step < KSTEPS; ++step) {
            const int cur = step & 1;
            if (step + 1 < KSTEPS) stage(cur ^ 1, (step + 1) << 6);
            compute(cur);
            __syncthreads();
        }
    } else {
        for (int step = 0; step < KSTEPS; ++step) {
            stage(0, step << 6);
            __syncthreads();
            compute(0);
            __syncthreads();
        }
    }

    // epilogue: D frag row=(lane>>4)*4+j, col=lane&15
    #pragma unroll
    for (int mi = 0; mi < MI; mi++) {
        #pragma unroll
        for (int j = 0; j < 4; j++) {
            const size_t row = bm + wr * 64 + mi * 16 + (lane >> 4) * 4 + j;
            if constexpr (RSCALE) {
                const float sc = rsqrtf(ssIn[row] * (1.0f / 1024.0f) + 1e-6f);
                #pragma unroll
                for (int ni = 0; ni < NI; ni++) acc[mi][ni][j] *= sc;
            }
            if constexpr (EPI == 3) {
                // RoPE on q,k sections. Wave col-span = 64 = one head; pairs (i,i+32) in (np,np+2).
                static_assert(BN == 128, "rope epilogue assumes BN=128");
                const int sec = (int)((bn + wc * 64) >> 10);   // 0=q,1=k,2=v
                if (sec < 2) {
                    const int t = (int)(row & (T_ - 1));
                    #pragma unroll
                    for (int np = 0; np < 2; np++) {
                        const int i1 = np * 16 + r16;          // 0..31
                        float c = cosT[t * 32 + i1], s = sinT[t * 32 + i1];
                        float x1 = acc[mi][np][j], x2 = acc[mi][np + 2][j];
                        acc[mi][np][j]     = c * x1 - s * x2;
                        acc[mi][np + 2][j] = s * x1 + c * x2;
                    }
                }
            }
            float ssq = 0.f;
            #pragma unroll
            for (int ni = 0; ni < NI; ni++) {
                const size_t col = bn + wc * (BN / 2) + ni * 16 + r16;
                float v = acc[mi][ni][j];
                if constexpr (EPI == 1) v += Res[row * N + col];
                if constexpr (EPI == 2) { v = fmaxf(v, 0.f); v *= v; }
                if constexpr (SSOUT) {
                    ssq += v * v;
                    xbOut[row * N + col] = f2bf(v);
                }
                if constexpr (OUTBF) {
                    ((ushort*)Cp)[row * N + col] = f2bf(v);
                } else if constexpr (EPI == 0) {
                    __builtin_nontemporal_store(v, (float*)Cp + row * N + col);
                } else {
                    ((float*)Cp)[row * N + col] = v;
                }
            }
            if constexpr (SSOUT) {
                #pragma unroll
                for (int off = 1; off < 16; off <<= 1) ssq += __shfl_xor(ssq, off);
                if (r16 == 0) atomicAdd(&ssOut[row], ssq);
            }
        }
    }
}

// ---------------- MFMA flash attention: single q-tile, dbuf K/V, 1 barrier/chunk ----------------
// Grid (16, B*H) = 512 blocks (2/CU). QBLK=64, KVBLK=64, 4 waves x 16 q-rows.
__global__ __launch_bounds__(256) void k_attn_sb(const ushort* __restrict__ qkv,
                                                 ushort* __restrict__ ctx) {
    __shared__ __align__(16) char lds[40960];
    // buf b at b*16384: K[64key][64d] swz, then Vt[64d][64key] swz at +8192
    // [32768,40960): Q then P [row][*] swz (128B rows)
    const int tid = threadIdx.x;
    const int w = tid >> 6, lane = tid & 63;
    const int r16 = lane & 15, kc = lane >> 4;
    const int rx = (r16 & 7) << 4;
    const int qb = blockIdx.x * 64;
    const int bh = blockIdx.y, b = bh >> 4, h = bh & 15;
    const size_t tok0 = (size_t)b * T_;
    const ushort* qg = qkv + (tok0 + qb) * (3 * D_) + h * DH_;
    const ushort* kg = qkv + tok0 * (3 * D_) + D_ + h * DH_;
    const ushort* vg = qkv + tok0 * (3 * D_) + 2 * D_ + h * DH_;
    const float SCALE_LOG2E = 0.125f * 1.44269504089f;

    const int srow = tid >> 3, sdcp = tid & 7;      // staging coords (2 slots/thread)
    const int vkey = tid >> 2, vdb = (tid & 3) * 16; // V transpose coords

    // ---- prologue: issue Q + K0 async, V0 -> regs ----
    #pragma unroll
    for (int i = 0; i < 2; i++) {
        int slot = i * 256 + tid;
        int row = slot >> 3, dcp = slot & 7;
        int d0 = (dcp ^ (row & 7)) * 8;
        async_copy16(qg + (size_t)row * (3 * D_) + d0, lds + 32768 + slot * 16);
    }
    #pragma unroll
    for (int i = 0; i < 2; i++) {
        int slot = i * 256 + tid;
        int row = slot >> 3, dcp = slot & 7;
        int d0 = (dcp ^ (row & 7)) * 8;
        async_copy16(kg + (size_t)row * (3 * D_) + d0, lds + slot * 16);
    }
    bf16x8 v0 = *(const bf16x8*)(vg + (size_t)vkey * (3 * D_) + vdb);
    bf16x8 v1 = *(const bf16x8*)(vg + (size_t)vkey * (3 * D_) + vdb + 8);
    __syncthreads();                       // Q,K0 in LDS; V0 in regs

    bf16x8 aq[2];
    #pragma unroll
    for (int ks = 0; ks < 2; ks++) {
        int row = w * 16 + r16;
        aq[ks] = *(const bf16x8*)(lds + 32768 + row * 128 + ((ks * 64 + kc * 16) ^ rx));
    }
    // write V0 transposed into buf0
    #pragma unroll
    for (int e = 0; e < 8; e++) {
        int d = vdb + e;
        *(ushort*)(lds + 8192 + d * 128 + ((vkey * 2) ^ ((d & 7) << 4))) = (ushort)v0[e];
        d = vdb + 8 + e;
        *(ushort*)(lds + 8192 + d * 128 + ((vkey * 2) ^ ((d & 7) << 4))) = (ushort)v1[e];
    }
    __syncthreads();                       // V0 visible

    f32x4 o[4];
    float m[4], l[4], corr[4];
    #pragma unroll
    for (int nd = 0; nd < 4; nd++) { f32x4 z = {0.f, 0.f, 0.f, 0.f}; o[nd] = z; }
    #pragma unroll
    for (int j = 0; j < 4; j++) { m[j] = -1e30f; l[j] = 0.f; }

    const int nch = blockIdx.x + 1;
    for (int ch = 0; ch < nch; ch++) {
        const int kb = ch << 6;
        const int cur = (ch & 1) * 16384;
        const int nxt = ((ch & 1) ^ 1) * 16384;
        const bool pre = (ch + 1 < nch);
        if (pre) {
            // issue next K chunk (async) + next V chunk (regs) early
            #pragma unroll
            for (int i = 0; i < 2; i++) {
                int slot = i * 256 + tid;
                int row = slot >> 3, dcp = slot & 7;
                int d0 = (dcp ^ (row & 7)) * 8;
                async_copy16(kg + (size_t)(kb + 64 + row) * (3 * D_) + d0, lds + nxt + slot * 16);
            }
            v0 = *(const bf16x8*)(vg + (size_t)(kb + 64 + vkey) * (3 * D_) + vdb);
            v1 = *(const bf16x8*)(vg + (size_t)(kb + 64 + vkey) * (3 * D_) + vdb + 8);
        }

        // S = Q K^T (64 q x 64 k) from buf cur
        f32x4 s[4];
        #pragma unroll
        for (int ni = 0; ni < 4; ni++) { f32x4 z = {0.f, 0.f, 0.f, 0.f}; s[ni] = z; }
        __builtin_amdgcn_s_setprio(1);
        #pragma unroll
        for (int ks = 0; ks < 2; ks++)
            #pragma unroll
            for (int ni = 0; ni < 4; ni++) {
                int row = ni * 16 + r16;
                bf16x8 kf = *(const bf16x8*)(lds + cur + row * 128 + ((ks * 64 + kc * 16) ^ rx));
                s[ni] = __builtin_amdgcn_mfma_f32_16x16x32_bf16(aq[ks], kf, s[ni], 0, 0, 0);
            }
        __builtin_amdgcn_s_setprio(0);

        const bool diag = (kb == qb);
        #pragma unroll
        for (int j = 0; j < 4; j++) {
            const int qrow = qb + w * 16 + kc * 4 + j;
            #pragma unroll
            for (int ni = 0; ni < 4; ni++) {
                float v = s[ni][j] * SCALE_LOG2E;
                if (diag) { int key = kb + ni * 16 + r16; if (key > qrow) v = -1e30f; }
                s[ni][j] = v;
            }
            float tmax = fmaxf(fmaxf(s[0][j], s[1][j]), fmaxf(s[2][j], s[3][j]));
            #pragma unroll
            for (int off = 1; off < 16; off <<= 1) tmax = fmaxf(tmax, __shfl_xor(tmax, off));
            float mn = fmaxf(m[j], tmax);
            corr[j] = exp2f(m[j] - mn);
            m[j] = mn;
            float ps = 0.f;
            #pragma unroll
            for (int ni = 0; ni < 4; ni++) {
                float p = exp2f(s[ni][j] - mn);
                s[ni][j] = p;
                ps += p;
            }
            #pragma unroll
            for (int off = 1; off < 16; off <<= 1) ps += __shfl_xor(ps, off);
            l[j] = l[j] * corr[j] + ps;
        }
        // P -> LDS bf16 (own wave's rows; same-wave read below needs no barrier)
        #pragma unroll
        for (int ni = 0; ni < 4; ni++)
            #pragma unroll
            for (int j = 0; j < 4; j++) {
                int row = w * 16 + kc * 4 + j;
                *(ushort*)(lds + 32768 + row * 128 + ((ni * 32 + r16 * 2) ^ ((row & 7) << 4))) = f2bf(s[ni][j]);
            }
        // rescale O
        #pragma unroll
        for (int nd = 0; nd < 4; nd++)
            #pragma unroll
            for (int j = 0; j < 4; j++) o[nd][j] *= corr[j];
        // O += P V from buf cur
        __builtin_amdgcn_s_setprio(1);
        #pragma unroll
        for (int ks = 0; ks < 2; ks++) {
            int prow = w * 16 + r16;
            bf16x8 pf = *(const bf16x8*)(lds + 32768 + prow * 128 + ((ks * 64 + kc * 16) ^ rx));
            #pragma unroll
            for (int nd = 0; nd < 4; nd++) {
                int drow = nd * 16 + r16;
                bf16x8 vf = *(const bf16x8*)(lds + cur + 8192 + drow * 128 + ((ks * 64 + kc * 16) ^ rx));
                o[nd] = __builtin_amdgcn_mfma_f32_16x16x32_bf16(pf, vf, o[nd], 0, 0, 0);
            }
        }
        __builtin_amdgcn_s_setprio(0);

        if (pre) {
            // write next V chunk transposed into buf nxt (nobody reads nxt until after barrier)
            #pragma unroll
            for (int e = 0; e < 8; e++) {
                int d = vdb + e;
                *(ushort*)(lds + nxt + 8192 + d * 128 + ((vkey * 2) ^ ((d & 7) << 4))) = (ushort)v0[e];
                d = vdb + 8 + e;
                *(ushort*)(lds + nxt + 8192 + d * 128 + ((vkey * 2) ^ ((d & 7) << 4))) = (ushort)v1[e];
            }
        }
        __syncthreads();   // drains next-K loads; next-V writes visible; all done with cur
    }

    #pragma unroll
    for (int j = 0; j < 4; j++) {
        float inv = 1.0f / l[j];
        int row = qb + w * 16 + kc * 4 + j;
        ushort* dst = ctx + (tok0 + row) * D_ + h * DH_;
        #pragma unroll
        for (int nd = 0; nd < 4; nd++)
            dst[nd * 16 + r16] = f2bf(o[nd][j] * inv);
    }
}

extern "C" void kernel_launch(void* const* d_in, const int* in_sizes, int n_in,
                              void* d_out, int out_size, void* d_ws, size_t ws_size,
                              hipStream_t stream) {
    const int*   xi   = (const int*)d_in[0];
    const float* emb  = (const float*)d_in[1];
    const float* Wqkv = (const float*)d_in[2];
    const float* Wout = (const float*)d_in[3];
    const float* W1   = (const float*)d_in[4];
    const float* W2   = (const float*)d_in[5];
    const float* lmh  = (const float*)d_in[6];
    float* out = (float*)d_out;

    const size_t NT = (size_t)B_ * T_;
    size_t off = 0;
    auto carve = [&](size_t bytes) -> char* {
        char* r = (char*)d_ws + off;
        off += (bytes + 255) & ~(size_t)255;
        return r;
    };
    float*  xbuf = (float*)carve(NT * D_ * 4);
    ushort* xb   = (ushort*)carve(NT * D_ * 2);     // bf16 mirror of residual stream
    ushort* qkv  = (ushort*)carve(NT * 3 * D_ * 2);
    ushort* ctxb = (ushort*)carve(NT * D_ * 2);
    ushort* hb   = (ushort*)carve(NT * 4 * D_ * 2);
    float*  cosT = (float*)carve(T_ * 32 * 4);
    float*  sinT = (float*)carve(T_ * 32 * 4);
    float*  ssA  = (float*)carve(17 * NT * 4);      // ss_q[0..8] then ss_f[0..7]
    float*  ss_q = ssA;
    float*  ss_f = ssA + 9 * NT;

    const size_t nWqkv = (size_t)L_ * 3 * D_ * D_;
    const size_t nWout = (size_t)L_ * D_ * D_;
    const size_t nW1   = (size_t)L_ * 4 * D_ * D_;
    const size_t nW2   = (size_t)L_ * 4 * D_ * D_;
    const size_t nLmh  = (size_t)V_ * D_;
    ushort* WqkvB = (ushort*)carve(nWqkv * 2);
    ushort* WoutB = (ushort*)carve(nWout * 2);
    ushort* W1B   = (ushort*)carve(nW1 * 2);
    ushort* W2B   = (ushort*)carve(nW2 * 2);
    ushort* lmhB  = (ushort*)carve(nLmh * 2);
    const bool preconv = (off <= ws_size);

    hipMemsetAsync(ssA, 0, 17 * NT * 4, stream);

    if (preconv) {
        k_cast<<<dim3(2048), dim3(256), 0, stream>>>((const float4*)Wqkv, (ushort4*)WqkvB, (int)(nWqkv / 4));
        k_cast<<<dim3(2048), dim3(256), 0, stream>>>((const float4*)Wout, (ushort4*)WoutB, (int)(nWout / 4));
        k_cast<<<dim3(2048), dim3(256), 0, stream>>>((const float4*)W1,   (ushort4*)W1B,   (int)(nW1 / 4));
        k_cast<<<dim3(2048), dim3(256), 0, stream>>>((const float4*)W2,   (ushort4*)W2B,   (int)(nW2 / 4));
        k_cast<<<dim3(2048), dim3(256), 0, stream>>>((const float4*)lmh,  (ushort4*)lmhB,  (int)(nLmh / 4));
    }

#define LAUNCH_GEMM(BN, EPI, OUTBF, RSC, SSO, GX, GY, Aq, Wb16, Wf32, Cq, Rq, ssin, ssout, xbo, Mv, Nv, Kv) \
    do {                                                                                     \
        if (preconv)                                                                         \
            k_mfma_gemm<BN, EPI, OUTBF, false, RSC, SSO><<<dim3(GX, GY), dim3(256), 0, stream>>>( \
                (const ushort*)(Aq), (const void*)(Wb16), (void*)(Cq), (Rq), cosT, sinT,     \
                (ssin), (ssout), (xbo), Mv, Nv, Kv);                                         \
        else                                                                                 \
            k_mfma_gemm<BN, EPI, OUTBF, true, RSC, SSO><<<dim3(GX, GY), dim3(256), 0, stream>>>( \
                (const ushort*)(Aq), (const void*)(Wf32), (void*)(Cq), (Rq), cosT, sinT,     \
                (ssin), (ssout), (xbo), Mv, Nv, Kv);                                         \
    } while (0)

    k_rope_tables<<<dim3(T_), dim3(32), 0, stream>>>(cosT, sinT);
    k_gather<<<dim3(NT), dim3(256), 0, stream>>>(xi, emb, xbuf, xb, ss_q);

    for (int l = 0; l < L_; l++) {
        // qkv = rope( rms-scale(x) * Wqkv^T )
        LAUNCH_GEMM(128, 3, true, true, false, 16, 24, xb,
                    WqkvB + (size_t)l * 3 * D_ * D_, Wqkv + (size_t)l * 3 * D_ * D_,
                    qkv, nullptr, ss_q + (size_t)l * NT, nullptr, nullptr, (int)NT, 3 * D_, D_);
        k_attn_sb<<<dim3(16, B_ * H_), dim3(256), 0, stream>>>(qkv, ctxb);
        // x += ctx*Wout^T ; emit xb mirror + ss for FFN norm
        LAUNCH_GEMM(64, 1, false, false, true, 16, 16, ctxb,
                    WoutB + (size_t)l * D_ * D_, Wout + (size_t)l * D_ * D_,
                    xbuf, xbuf, nullptr, ss_f + (size_t)l * NT, xb, (int)NT, D_, D_);
        // h = relu( rms-scale(x)*W1^T )^2
        LAUNCH_GEMM(128, 2, true, true, false, 16, 32, xb,
                    W1B + (size_t)l * 4 * D_ * D_, W1 + (size_t)l * 4 * D_ * D_,
                    hb, nullptr, ss_f + (size_t)l * NT, nullptr, nullptr, (int)NT, 4 * D_, D_);
        // x += h*W2^T ; emit xb mirror + ss for next qkv norm (or lm_head)
        LAUNCH_GEMM(64, 1, false, false, true, 16, 16, hb,
                    W2B + (size_t)l * 4 * D_ * D_, W2 + (size_t)l * 4 * D_ * D_,
                    xbuf, xbuf, nullptr, ss_q + (size_t)(l + 1) * NT, xb, (int)NT, D_, 4 * D_);
    }
    // logits = rms-scale(x) * lmh^T
    LAUNCH_GEMM(256, 0, false, true, false, 16, 125, xb, lmhB, lmh, out, nullptr,
                ss_q + (size_t)L_ * NT, nullptr, nullptr, (int)NT, V_, D_);
#undef LAUNCH_GEMM
}

// Round 12
// 1877.692 us; speedup vs baseline: 1.0517x; 1.0517x over previous
//
#include <hip/hip_runtime.h>
#include <hip/hip_bf16.h>
#include <cmath>
#include <cstdint>

#define B_  2
#define T_  1024
#define V_  32000
#define D_  1024
#define H_  16
#define L_  8
#define DH_ 64

typedef __attribute__((ext_vector_type(8))) short bf16x8;
typedef __attribute__((ext_vector_type(4))) float f32x4;

__device__ __forceinline__ ushort f2bf(float f) {
    union { float f; uint32_t u; } v; v.f = f;
    uint32_t r = v.u + 0x7FFFu + ((v.u >> 16) & 1u);
    return (ushort)(r >> 16);
}
__device__ __forceinline__ float bf2f(ushort u) {
    union { uint32_t u; float f; } v; v.u = ((uint32_t)u) << 16;
    return v.f;
}

__device__ __forceinline__ void async_copy16(const void* g, void* l) {
    __builtin_amdgcn_global_load_lds(
        (const __attribute__((address_space(1))) void*)g,
        (__attribute__((address_space(3))) void*)l, 16, 0, 0);
}

// ---------------- fp32 -> bf16 cast (weights) ----------------
__global__ __launch_bounds__(256) void k_cast(const float4* __restrict__ in,
                                              ushort4* __restrict__ out, int n4) {
    for (int i = blockIdx.x * 256 + threadIdx.x; i < n4; i += gridDim.x * 256) {
        float4 v = in[i];
        out[i] = make_ushort4(f2bf(v.x), f2bf(v.y), f2bf(v.z), f2bf(v.w));
    }
}

// ---------------- RoPE tables: cos/sin (T, 32) ----------------
__global__ void k_rope_tables(float* __restrict__ cosT, float* __restrict__ sinT) {
    int t = blockIdx.x;
    int i = threadIdx.x;           // 0..31
    float invf = (i < 16) ? powf(1000.0f, -(float)i / 16.0f) : 0.0f;
    float th = (float)t * invf;
    cosT[t * 32 + i] = cosf(th);
    sinT[t * 32 + i] = sinf(th);
}

// ---------------- Embedding gather (fp32 x) ----------------
__global__ __launch_bounds__(256) void k_gather(const int* __restrict__ idx,
                                                const float* __restrict__ emb,
                                                float* __restrict__ x) {
    int row = blockIdx.x;
    int id = idx[row];
    const float4* src = (const float4*)(emb + (size_t)id * D_);
    float4* dst = (float4*)(x + (size_t)row * D_);
    dst[threadIdx.x] = src[threadIdx.x];
}

// ---------------- RMSNorm: bf16 out ----------------
__global__ __launch_bounds__(256) void k_rmsnorm(const float* __restrict__ x,
                                                 ushort* __restrict__ out) {
    int row = blockIdx.x;
    const float4* xr = (const float4*)(x + (size_t)row * D_);
    float4 v = xr[threadIdx.x];
    float ss = v.x * v.x + v.y * v.y + v.z * v.z + v.w * v.w;
    #pragma unroll
    for (int off = 1; off < 64; off <<= 1) ss += __shfl_xor(ss, off);
    __shared__ float wsum[4];
    int lane = threadIdx.x & 63, wv = threadIdx.x >> 6;
    if (lane == 0) wsum[wv] = ss;
    __syncthreads();
    float tot = wsum[0] + wsum[1] + wsum[2] + wsum[3];
    float inv = rsqrtf(tot * (1.0f / D_) + 1e-6f);
    ushort4 r = make_ushort4(f2bf(v.x * inv), f2bf(v.y * inv), f2bf(v.z * inv), f2bf(v.w * inv));
    *(ushort4*)(out + (size_t)row * D_ + threadIdx.x * 4) = r;
}

// ---------------- MFMA GEMM (layer GEMMs): BM=128, BK=64, T2 swizzle, T1 swizzle ----------------
// BN<=128: prefetch double-buffer. BN=256: single buffer (fallback only).
// EPI: 0 none(+nontemporal), 1 +Res(fp32), 2 relu^2, 3 RoPE(qkv).
template<int BN, int EPI, bool OUTBF, bool CONVB>
__global__ __launch_bounds__(256, 2) void k_mfma_gemm(const ushort* __restrict__ A,
                                                      const void* __restrict__ Wp,
                                                      void* __restrict__ Cp,
                                                      const float* __restrict__ Res,
                                                      const float* __restrict__ cosT,
                                                      const float* __restrict__ sinT,
                                                      int M, int N, int K) {
    constexpr int BM = 128;
    constexpr int MI = 4;
    constexpr int NI = BN / 32;
    constexpr bool DBUF = (BN <= 128);
    constexpr int NB = DBUF ? 2 : 1;
    __shared__ ushort As[NB][BM][64];   // swizzled: chunk c of row r at byte ((c^(r&7))<<4)
    __shared__ ushort Bs[NB][BN][64];
    const int tid = threadIdx.x;
    const int wid = tid >> 6, lane = tid & 63;
    const int wr = wid >> 1, wc = wid & 1;
    const int r16 = lane & 15, kc = lane >> 4;
    const int rx = (r16 & 7) << 4;
    const int srow8 = tid >> 3;
    const int sdcp = tid & 7;

    const int nwg = gridDim.x * gridDim.y;
    int orig = blockIdx.y * gridDim.x + blockIdx.x;
    int swz = (nwg & 7) ? orig : ((orig & 7) * (nwg >> 3) + (orig >> 3));
    const size_t bm = (size_t)(swz % gridDim.x) * BM;
    const size_t bn = (size_t)(swz / gridDim.x) * BN;

    auto stage = [&](int buf, int k0) {
        #pragma unroll
        for (int i = 0; i < 4; i++) {
            const int row = i * 32 + srow8;
            const ushort* g = A + (bm + row) * (size_t)K + k0 + ((sdcp ^ (row & 7)) * 8);
            async_copy16(g, (char*)As + buf * (BM * 128) + (i * 256 + tid) * 16);
        }
        if constexpr (!CONVB) {
            const ushort* Wb = (const ushort*)Wp;
            #pragma unroll
            for (int i = 0; i < BN / 32; i++) {
                const int row = i * 32 + srow8;
                const ushort* g = Wb + (bn + row) * (size_t)K + k0 + ((sdcp ^ (row & 7)) * 8);
                async_copy16(g, (char*)Bs + buf * (BN * 128) + (i * 256 + tid) * 16);
            }
        } else {
            const float* Wf = (const float*)Wp;
            #pragma unroll
            for (int i = 0; i < BN / 32; i++) {
                const int row = i * 32 + srow8;
                const float* src = Wf + (bn + row) * (size_t)K + k0 + sdcp * 8;
                float4 v0 = *(const float4*)(src);
                float4 v1 = *(const float4*)(src + 4);
                union { ushort u[8]; bf16x8 v; } tmp;
                tmp.u[0] = f2bf(v0.x); tmp.u[1] = f2bf(v0.y);
                tmp.u[2] = f2bf(v0.z); tmp.u[3] = f2bf(v0.w);
                tmp.u[4] = f2bf(v1.x); tmp.u[5] = f2bf(v1.y);
                tmp.u[6] = f2bf(v1.z); tmp.u[7] = f2bf(v1.w);
                *(bf16x8*)((char*)Bs + buf * (BN * 128) + row * 128 + ((sdcp ^ (row & 7)) << 4)) = tmp.v;
            }
        }
    };

    f32x4 acc[MI][NI];
    #pragma unroll
    for (int mi = 0; mi < MI; mi++)
        #pragma unroll
        for (int ni = 0; ni < NI; ni++) {
            f32x4 z = {0.f, 0.f, 0.f, 0.f};
            acc[mi][ni] = z;
        }

    auto compute = [&](int buf) {
        #pragma unroll
        for (int kk = 0; kk < 2; kk++) {
            bf16x8 af[MI], bfr[NI];
            #pragma unroll
            for (int mi = 0; mi < MI; mi++)
                af[mi] = *(const bf16x8*)((const char*)As + buf * (BM * 128) +
                                          (wr * 64 + mi * 16 + r16) * 128 +
                                          ((kk * 64 + kc * 16) ^ rx));
            #pragma unroll
            for (int ni = 0; ni < NI; ni++)
                bfr[ni] = *(const bf16x8*)((const char*)Bs + buf * (BN * 128) +
                                           (wc * (BN / 2) + ni * 16 + r16) * 128 +
                                           ((kk * 64 + kc * 16) ^ rx));
            #pragma unroll
            for (int mi = 0; mi < MI; mi++)
                #pragma unroll
                for (int ni = 0; ni < NI; ni++)
                    acc[mi][ni] = __builtin_amdgcn_mfma_f32_16x16x32_bf16(af[mi], bfr[ni],
                                                                          acc[mi][ni], 0, 0, 0);
        }
    };

    const int KSTEPS = K >> 6;
    if constexpr (DBUF) {
        stage(0, 0);
        __syncthreads();
        for (int step = 0; step < KSTEPS; ++step) {
            const int cur = step & 1;
            if (step + 1 < KSTEPS) stage(cur ^ 1, (step + 1) << 6);
            compute(cur);
            __syncthreads();
        }
    } else {
        for (int step = 0; step < KSTEPS; ++step) {
            stage(0, step << 6);
            __syncthreads();
            compute(0);
            __syncthreads();
        }
    }

    #pragma unroll
    for (int mi = 0; mi < MI; mi++) {
        #pragma unroll
        for (int j = 0; j < 4; j++) {
            const size_t row = bm + wr * 64 + mi * 16 + (lane >> 4) * 4 + j;
            if constexpr (EPI == 3) {
                static_assert(BN == 128, "rope epilogue assumes BN=128");
                const int sec = (int)((bn + wc * 64) >> 10);   // 0=q,1=k,2=v
                if (sec < 2) {
                    const int t = (int)(row & (T_ - 1));
                    #pragma unroll
                    for (int np = 0; np < 2; np++) {
                        const int i1 = np * 16 + r16;          // 0..31
                        float c = cosT[t * 32 + i1], s = sinT[t * 32 + i1];
                        float x1 = acc[mi][np][j], x2 = acc[mi][np + 2][j];
                        acc[mi][np][j]     = c * x1 - s * x2;
                        acc[mi][np + 2][j] = s * x1 + c * x2;
                    }
                }
            }
            #pragma unroll
            for (int ni = 0; ni < NI; ni++) {
                const size_t col = bn + wc * (BN / 2) + ni * 16 + r16;
                float v = acc[mi][ni][j];
                if constexpr (EPI == 1) v += Res[row * N + col];
                if constexpr (EPI == 2) { v = fmaxf(v, 0.f); v *= v; }
                if constexpr (OUTBF) {
                    ((ushort*)Cp)[row * N + col] = f2bf(v);
                } else if constexpr (EPI == 0) {
                    __builtin_nontemporal_store(v, (float*)Cp + row * N + col);
                } else {
                    ((float*)Cp)[row * N + col] = v;
                }
            }
        }
    }
}

// ---------------- 256x256 8-wave phase-interleaved GEMM (lm_head) ----------------
// 512 threads (2x4 waves), BK=64, full 2-tile LDS double buffer (128 KB),
// 4 quadrant-phases per K-tile each issuing 2 global_load_lds quarters of tile t+1,
// A/B fragments each loaded once per tile, setprio around MFMA clusters,
// one __syncthreads per tile (drain+barrier). Buffer stride = 32768 B (256 rows x 128 B).
__global__ __launch_bounds__(512, 2) void k_gemm256(const ushort* __restrict__ A,
                                                    const ushort* __restrict__ Wb,
                                                    float* __restrict__ C,
                                                    int M, int N, int K) {
    __shared__ ushort As[2][256][64];   // 2 x 32 KB
    __shared__ ushort Bs[2][256][64];   // 2 x 32 KB
    constexpr int BUFB = 256 * 64 * 2;  // 32768 bytes per buffer
    const int tid = threadIdx.x;        // 0..511
    const int wid = tid >> 6, lane = tid & 63;
    const int wr = wid >> 2, wc = wid & 3;     // 2 x 4 wave grid
    const int r16 = lane & 15, kc = lane >> 4;
    const int rx = (r16 & 7) << 4;

    const int nwg = gridDim.x * gridDim.y;
    int orig = blockIdx.y * gridDim.x + blockIdx.x;
    int swz = (nwg & 7) ? orig : ((orig & 7) * (nwg >> 3) + (orig >> 3));
    const size_t bm = (size_t)(swz % gridDim.x) * 256;
    const size_t bn = (size_t)(swz / gridDim.x) * 256;

    // staging: 2048 slots per matrix per tile; slot s: row=s>>3, chunk=s&7; thread does s=q*512+tid
    auto stageq = [&](int buf, int k0, int q) {
        const int s = q * 512 + tid;
        const int row = s >> 3, ch = s & 7;
        const int col = (ch ^ (row & 7)) * 8;
        async_copy16(A + (bm + row) * (size_t)K + k0 + col, (char*)As + buf * BUFB + s * 16);
        async_copy16(Wb + (bn + row) * (size_t)K + k0 + col, (char*)Bs + buf * BUFB + s * 16);
    };

    f32x4 acc[8][4];
    #pragma unroll
    for (int mi = 0; mi < 8; mi++)
        #pragma unroll
        for (int ni = 0; ni < 4; ni++) {
            f32x4 z = {0.f, 0.f, 0.f, 0.f};
            acc[mi][ni] = z;
        }

    const int KS = K >> 6;              // 16 tiles
    #pragma unroll
    for (int q = 0; q < 4; q++) stageq(0, 0, q);
    __syncthreads();                    // tile 0 resident

    for (int t = 0; t < KS; ++t) {
        const int cur = t & 1, nxt = cur ^ 1;
        const bool pre = (t + 1 < KS);
        const char* Ab = (const char*)As + cur * BUFB;
        const char* Bb = (const char*)Bs + cur * BUFB;

        bf16x8 af[4][2], bf0[2][2], bf1[2][2];

        auto loadA = [&](int half) {
            #pragma unroll
            for (int mi = 0; mi < 4; mi++)
                #pragma unroll
                for (int kk = 0; kk < 2; kk++)
                    af[mi][kk] = *(const bf16x8*)(Ab + (wr * 128 + half * 64 + mi * 16 + r16) * 128 +
                                                  ((kk * 64 + kc * 16) ^ rx));
        };
        auto loadB = [&](bf16x8 (&bf)[2][2], int half) {
            #pragma unroll
            for (int ni = 0; ni < 2; ni++)
                #pragma unroll
                for (int kk = 0; kk < 2; kk++)
                    bf[ni][kk] = *(const bf16x8*)(Bb + (wc * 64 + half * 32 + ni * 16 + r16) * 128 +
                                                  ((kk * 64 + kc * 16) ^ rx));
        };
        auto quad = [&](int mh, bf16x8 (&bf)[2][2], int nh) {
            __builtin_amdgcn_s_setprio(1);
            #pragma unroll
            for (int kk = 0; kk < 2; kk++)
                #pragma unroll
                for (int mi = 0; mi < 4; mi++)
                    #pragma unroll
                    for (int ni = 0; ni < 2; ni++)
                        acc[mh * 4 + mi][nh * 2 + ni] =
                            __builtin_amdgcn_mfma_f32_16x16x32_bf16(af[mi][kk], bf[ni][kk],
                                                                    acc[mh * 4 + mi][nh * 2 + ni], 0, 0, 0);
            __builtin_amdgcn_s_setprio(0);
        };

        // phase 0: (qm0, qn0)
        if (pre) stageq(nxt, (t + 1) << 6, 0);
        loadA(0); loadB(bf0, 0);
        quad(0, bf0, 0);
        // phase 1: (qm0, qn1) — reuse af
        if (pre) stageq(nxt, (t + 1) << 6, 1);
        loadB(bf1, 1);
        quad(0, bf1, 1);
        // phase 2: (qm1, qn1) — reuse bf1
        if (pre) stageq(nxt, (t + 1) << 6, 2);
        loadA(1);
        quad(1, bf1, 1);
        // phase 3: (qm1, qn0) — reuse af, bf0
        if (pre) stageq(nxt, (t + 1) << 6, 3);
        quad(1, bf0, 0);

        __syncthreads();   // vmcnt(0)+lgkmcnt(0) drain + barrier: tile t+1 resident, cur reusable
    }

    // epilogue: row = bm + wr*128 + mi*16 + (lane>>4)*4 + j ; col = bn + wc*64 + ni*16 + r16
    #pragma unroll
    for (int mi = 0; mi < 8; mi++) {
        #pragma unroll
        for (int j = 0; j < 4; j++) {
            const size_t row = bm + wr * 128 + mi * 16 + (lane >> 4) * 4 + j;
            #pragma unroll
            for (int ni = 0; ni < 4; ni++) {
                const size_t col = bn + wc * 64 + ni * 16 + r16;
                __builtin_nontemporal_store(acc[mi][ni][j], C + row * (size_t)N + col);
            }
        }
    }
}

// ---------------- MFMA flash attention: paired causal tiles ----------------
__global__ __launch_bounds__(256) void k_attn_pair(const ushort* __restrict__ qkv,
                                                   ushort* __restrict__ ctx) {
    __shared__ __align__(16) char lds[32768];
    const int tid = threadIdx.x;
    const int w = tid >> 6, lane = tid & 63;
    const int r16 = lane & 15, kc = lane >> 4;
    const int rx = (r16 & 7) << 4;
    const int ip = blockIdx.x;                 // pair index 0..7
    const int qb[2] = { ip * 64, (15 - ip) * 64 };   // 0=lo, 1=hi
    const int bh = blockIdx.y, b = bh >> 4, h = bh & 15;
    const size_t tok0 = (size_t)b * T_;
    const ushort* kg = qkv + tok0 * (3 * D_) + D_ + h * DH_;
    const ushort* vg = qkv + tok0 * (3 * D_) + 2 * D_ + h * DH_;
    const float SCALE_LOG2E = 0.125f * 1.44269504089f;

    #pragma unroll
    for (int t = 0; t < 2; t++) {
        const ushort* qg = qkv + (tok0 + qb[t]) * (3 * D_) + h * DH_;
        #pragma unroll
        for (int i = 0; i < 2; i++) {
            int slot = i * 256 + tid;
            int row = slot >> 3, dcp = slot & 7;
            int d0 = (dcp ^ (row & 7)) * 8;
            async_copy16(qg + (size_t)row * (3 * D_) + d0, lds + 16384 + t * 8192 + slot * 16);
        }
    }
    __syncthreads();
    bf16x8 aq[2][2];
    #pragma unroll
    for (int t = 0; t < 2; t++)
        #pragma unroll
        for (int ks = 0; ks < 2; ks++) {
            int row = w * 16 + r16;
            aq[t][ks] = *(const bf16x8*)(lds + 16384 + t * 8192 + row * 128 +
                                         ((ks * 64 + kc * 16) ^ rx));
        }

    f32x4 o[2][4];
    float m[2][4], l[2][4];
    #pragma unroll
    for (int t = 0; t < 2; t++)
        #pragma unroll
        for (int nd = 0; nd < 4; nd++) {
            f32x4 z = {0.f, 0.f, 0.f, 0.f};
            o[t][nd] = z;
            m[t][nd] = -1e30f; l[t][nd] = 0.f;
        }

    const int nch = 16 - ip;
    for (int ch = 0; ch < nch; ch++) {
        const int kb = ch << 6;
        __syncthreads();
        #pragma unroll
        for (int i = 0; i < 2; i++) {
            int slot = i * 256 + tid;
            int row = slot >> 3, dcp = slot & 7;
            int d0 = (dcp ^ (row & 7)) * 8;
            async_copy16(kg + (size_t)(kb + row) * (3 * D_) + d0, lds + slot * 16);
        }
        {
            int key = tid >> 2, dbase = (tid & 3) * 16;
            const ushort* src = vg + (size_t)(kb + key) * (3 * D_) + dbase;
            bf16x8 v0 = *(const bf16x8*)(src);
            bf16x8 v1 = *(const bf16x8*)(src + 8);
            #pragma unroll
            for (int e = 0; e < 8; e++) {
                int d = dbase + e;
                *(ushort*)(lds + 8192 + d * 128 + ((key * 2) ^ ((d & 7) << 4))) = (ushort)v0[e];
                d = dbase + 8 + e;
                *(ushort*)(lds + 8192 + d * 128 + ((key * 2) ^ ((d & 7) << 4))) = (ushort)v1[e];
            }
        }
        __syncthreads();

        const int nact = (ch <= ip) ? 2 : 1;
        for (int tt = 0; tt < nact; tt++) {
            const int t = (tt == 0) ? 1 : 0;   // hi first, then lo
            const int pq = 16384 + t * 8192;
            f32x4 s[4];
            #pragma unroll
            for (int ni = 0; ni < 4; ni++) { f32x4 z = {0.f, 0.f, 0.f, 0.f}; s[ni] = z; }
            __builtin_amdgcn_s_setprio(1);
            #pragma unroll
            for (int ks = 0; ks < 2; ks++)
                #pragma unroll
                for (int ni = 0; ni < 4; ni++) {
                    int row = ni * 16 + r16;
                    bf16x8 kf = *(const bf16x8*)(lds + row * 128 + ((ks * 64 + kc * 16) ^ rx));
                    s[ni] = __builtin_amdgcn_mfma_f32_16x16x32_bf16(aq[t][ks], kf, s[ni], 0, 0, 0);
                }
            __builtin_amdgcn_s_setprio(0);

            const bool diag = (kb == qb[t]);
            float corr[4];
            #pragma unroll
            for (int j = 0; j < 4; j++) {
                const int qrow = qb[t] + w * 16 + kc * 4 + j;
                #pragma unroll
                for (int ni = 0; ni < 4; ni++) {
                    float v = s[ni][j] * SCALE_LOG2E;
                    if (diag) { int key = kb + ni * 16 + r16; if (key > qrow) v = -1e30f; }
                    s[ni][j] = v;
                }
                float tmax = fmaxf(fmaxf(s[0][j], s[1][j]), fmaxf(s[2][j], s[3][j]));
                #pragma unroll
                for (int off = 1; off < 16; off <<= 1) tmax = fmaxf(tmax, __shfl_xor(tmax, off));
                float mn = fmaxf(m[t][j], tmax);
                corr[j] = exp2f(m[t][j] - mn);
                m[t][j] = mn;
                float ps = 0.f;
                #pragma unroll
                for (int ni = 0; ni < 4; ni++) {
                    float p = exp2f(s[ni][j] - mn);
                    s[ni][j] = p;
                    ps += p;
                }
                #pragma unroll
                for (int off = 1; off < 16; off <<= 1) ps += __shfl_xor(ps, off);
                l[t][j] = l[t][j] * corr[j] + ps;
            }
            #pragma unroll
            for (int ni = 0; ni < 4; ni++)
                #pragma unroll
                for (int j = 0; j < 4; j++) {
                    int row = w * 16 + kc * 4 + j;
                    *(ushort*)(lds + pq + row * 128 + ((ni * 32 + r16 * 2) ^ ((row & 7) << 4))) = f2bf(s[ni][j]);
                }
            #pragma unroll
            for (int nd = 0; nd < 4; nd++)
                #pragma unroll
                for (int j = 0; j < 4; j++) o[t][nd][j] *= corr[j];
            __builtin_amdgcn_s_setprio(1);
            #pragma unroll
            for (int ks = 0; ks < 2; ks++) {
                int prow = w * 16 + r16;
                bf16x8 pf = *(const bf16x8*)(lds + pq + prow * 128 + ((ks * 64 + kc * 16) ^ rx));
                #pragma unroll
                for (int nd = 0; nd < 4; nd++) {
                    int drow = nd * 16 + r16;
                    bf16x8 vf = *(const bf16x8*)(lds + 8192 + drow * 128 + ((ks * 64 + kc * 16) ^ rx));
                    o[t][nd] = __builtin_amdgcn_mfma_f32_16x16x32_bf16(pf, vf, o[t][nd], 0, 0, 0);
                }
            }
            __builtin_amdgcn_s_setprio(0);
        }
    }

    #pragma unroll
    for (int t = 0; t < 2; t++)
        #pragma unroll
        for (int j = 0; j < 4; j++) {
            float inv = 1.0f / l[t][j];
            int row = qb[t] + w * 16 + kc * 4 + j;
            ushort* dst = ctx + (tok0 + row) * D_ + h * DH_;
            #pragma unroll
            for (int nd = 0; nd < 4; nd++)
                dst[nd * 16 + r16] = f2bf(o[t][nd][j] * inv);
        }
}

extern "C" void kernel_launch(void* const* d_in, const int* in_sizes, int n_in,
                              void* d_out, int out_size, void* d_ws, size_t ws_size,
                              hipStream_t stream) {
    const int*   xi   = (const int*)d_in[0];
    const float* emb  = (const float*)d_in[1];
    const float* Wqkv = (const float*)d_in[2];
    const float* Wout = (const float*)d_in[3];
    const float* W1   = (const float*)d_in[4];
    const float* W2   = (const float*)d_in[5];
    const float* lmh  = (const float*)d_in[6];
    float* out = (float*)d_out;

    const size_t NT = (size_t)B_ * T_;
    size_t off = 0;
    auto carve = [&](size_t bytes) -> char* {
        char* r = (char*)d_ws + off;
        off += (bytes + 255) & ~(size_t)255;
        return r;
    };
    float*  xbuf = (float*)carve(NT * D_ * 4);
    ushort* qkv  = (ushort*)carve(NT * 3 * D_ * 2);
    ushort* nb   = (ushort*)carve(NT * D_ * 2);
    ushort* ctxb = (ushort*)carve(NT * D_ * 2);
    ushort* hb   = (ushort*)carve(NT * 4 * D_ * 2);
    float*  cosT = (float*)carve(T_ * 32 * 4);
    float*  sinT = (float*)carve(T_ * 32 * 4);

    const size_t nWqkv = (size_t)L_ * 3 * D_ * D_;
    const size_t nWout = (size_t)L_ * D_ * D_;
    const size_t nW1   = (size_t)L_ * 4 * D_ * D_;
    const size_t nW2   = (size_t)L_ * 4 * D_ * D_;
    const size_t nLmh  = (size_t)V_ * D_;
    ushort* WqkvB = (ushort*)carve(nWqkv * 2);
    ushort* WoutB = (ushort*)carve(nWout * 2);
    ushort* W1B   = (ushort*)carve(nW1 * 2);
    ushort* W2B   = (ushort*)carve(nW2 * 2);
    ushort* lmhB  = (ushort*)carve(nLmh * 2);
    const bool preconv = (off <= ws_size);

    if (preconv) {
        k_cast<<<dim3(2048), dim3(256), 0, stream>>>((const float4*)Wqkv, (ushort4*)WqkvB, (int)(nWqkv / 4));
        k_cast<<<dim3(2048), dim3(256), 0, stream>>>((const float4*)Wout, (ushort4*)WoutB, (int)(nWout / 4));
        k_cast<<<dim3(2048), dim3(256), 0, stream>>>((const float4*)W1,   (ushort4*)W1B,   (int)(nW1 / 4));
        k_cast<<<dim3(2048), dim3(256), 0, stream>>>((const float4*)W2,   (ushort4*)W2B,   (int)(nW2 / 4));
        k_cast<<<dim3(2048), dim3(256), 0, stream>>>((const float4*)lmh,  (ushort4*)lmhB,  (int)(nLmh / 4));
    }

#define LAUNCH_GEMM(BN, EPI, OUTBF, GX, GY, Aq, Wb16, Wf32, Cq, Rq, Mv, Nv, Kv)              \
    do {                                                                                     \
        if (preconv)                                                                         \
            k_mfma_gemm<BN, EPI, OUTBF, false><<<dim3(GX, GY), dim3(256), 0, stream>>>(      \
                (const ushort*)(Aq), (const void*)(Wb16), (void*)(Cq), (Rq), cosT, sinT,     \
                Mv, Nv, Kv);                                                                 \
        else                                                                                 \
            k_mfma_gemm<BN, EPI, OUTBF, true><<<dim3(GX, GY), dim3(256), 0, stream>>>(       \
                (const ushort*)(Aq), (const void*)(Wf32), (void*)(Cq), (Rq), cosT, sinT,     \
                Mv, Nv, Kv);                                                                 \
    } while (0)

    k_rope_tables<<<dim3(T_), dim3(32), 0, stream>>>(cosT, sinT);
    k_gather<<<dim3(NT), dim3(256), 0, stream>>>(xi, emb, xbuf);

    for (int l = 0; l < L_; l++) {
        k_rmsnorm<<<dim3(NT), dim3(256), 0, stream>>>(xbuf, nb);
        LAUNCH_GEMM(128, 3, true, 16, 24, nb,
                    WqkvB + (size_t)l * 3 * D_ * D_, Wqkv + (size_t)l * 3 * D_ * D_,
                    qkv, nullptr, (int)NT, 3 * D_, D_);
        k_attn_pair<<<dim3(8, B_ * H_), dim3(256), 0, stream>>>(qkv, ctxb);
        LAUNCH_GEMM(64, 1, false, 16, 16, ctxb,
                    WoutB + (size_t)l * D_ * D_, Wout + (size_t)l * D_ * D_,
                    xbuf, xbuf, (int)NT, D_, D_);
        k_rmsnorm<<<dim3(NT), dim3(256), 0, stream>>>(xbuf, nb);
        LAUNCH_GEMM(128, 2, true, 16, 32, nb,
                    W1B + (size_t)l * 4 * D_ * D_, W1 + (size_t)l * 4 * D_ * D_,
                    hb, nullptr, (int)NT, 4 * D_, D_);
        LAUNCH_GEMM(64, 1, false, 16, 16, hb,
                    W2B + (size_t)l * 4 * D_ * D_, W2 + (size_t)l * 4 * D_ * D_,
                    xbuf, xbuf, (int)NT, D_, 4 * D_);
    }
    k_rmsnorm<<<dim3(NT), dim3(256), 0, stream>>>(xbuf, nb);
    if (preconv)
        k_gemm256<<<dim3(8, 125), dim3(512), 0, stream>>>(nb, lmhB, out, (int)NT, V_, D_);
    else
        LAUNCH_GEMM(256, 0, false, 16, 125, nb, lmhB, lmh, out, nullptr, (int)NT, V_, D_);
#undef LAUNCH_GEMM
}

// Round 13
// 1840.212 us; speedup vs baseline: 1.0732x; 1.0204x over previous
//
#include <hip/hip_runtime.h>
#include <hip/hip_bf16.h>
#include <cmath>
#include <cstdint>

#define B_  2
#define T_  1024
#define V_  32000
#define D_  1024
#define H_  16
#define L_  8
#define DH_ 64

typedef __attribute__((ext_vector_type(8))) short bf16x8;
typedef __attribute__((ext_vector_type(4))) float f32x4;

__device__ __forceinline__ ushort f2bf(float f) {
    union { float f; uint32_t u; } v; v.f = f;
    uint32_t r = v.u + 0x7FFFu + ((v.u >> 16) & 1u);
    return (ushort)(r >> 16);
}
__device__ __forceinline__ float bf2f(ushort u) {
    union { uint32_t u; float f; } v; v.u = ((uint32_t)u) << 16;
    return v.f;
}

__device__ __forceinline__ void async_copy16(const void* g, void* l) {
    __builtin_amdgcn_global_load_lds(
        (const __attribute__((address_space(1))) void*)g,
        (__attribute__((address_space(3))) void*)l, 16, 0, 0);
}

// ---------------- fp32 -> bf16 cast (weights) ----------------
__global__ __launch_bounds__(256) void k_cast(const float4* __restrict__ in,
                                              ushort4* __restrict__ out, int n4) {
    for (int i = blockIdx.x * 256 + threadIdx.x; i < n4; i += gridDim.x * 256) {
        float4 v = in[i];
        out[i] = make_ushort4(f2bf(v.x), f2bf(v.y), f2bf(v.z), f2bf(v.w));
    }
}

// ---------------- RoPE tables: cos/sin (T, 32) ----------------
__global__ void k_rope_tables(float* __restrict__ cosT, float* __restrict__ sinT) {
    int t = blockIdx.x;
    int i = threadIdx.x;           // 0..31
    float invf = (i < 16) ? powf(1000.0f, -(float)i / 16.0f) : 0.0f;
    float th = (float)t * invf;
    cosT[t * 32 + i] = cosf(th);
    sinT[t * 32 + i] = sinf(th);
}

// ---------------- Embedding gather (fp32 x) ----------------
__global__ __launch_bounds__(256) void k_gather(const int* __restrict__ idx,
                                                const float* __restrict__ emb,
                                                float* __restrict__ x) {
    int row = blockIdx.x;
    int id = idx[row];
    const float4* src = (const float4*)(emb + (size_t)id * D_);
    float4* dst = (float4*)(x + (size_t)row * D_);
    dst[threadIdx.x] = src[threadIdx.x];
}

// ---------------- RMSNorm: bf16 out ----------------
__global__ __launch_bounds__(256) void k_rmsnorm(const float* __restrict__ x,
                                                 ushort* __restrict__ out) {
    int row = blockIdx.x;
    const float4* xr = (const float4*)(x + (size_t)row * D_);
    float4 v = xr[threadIdx.x];
    float ss = v.x * v.x + v.y * v.y + v.z * v.z + v.w * v.w;
    #pragma unroll
    for (int off = 1; off < 64; off <<= 1) ss += __shfl_xor(ss, off);
    __shared__ float wsum[4];
    int lane = threadIdx.x & 63, wv = threadIdx.x >> 6;
    if (lane == 0) wsum[wv] = ss;
    __syncthreads();
    float tot = wsum[0] + wsum[1] + wsum[2] + wsum[3];
    float inv = rsqrtf(tot * (1.0f / D_) + 1e-6f);
    ushort4 r = make_ushort4(f2bf(v.x * inv), f2bf(v.y * inv), f2bf(v.z * inv), f2bf(v.w * inv));
    *(ushort4*)(out + (size_t)row * D_ + threadIdx.x * 4) = r;
}

// ---------------- MFMA GEMM: BM=128, BK=64, T2 swizzle, T1 swizzle ----------------
// BN<=128: prefetch double-buffer. BN=256: single buffer, high-intensity (lm_head).
// EPI: 0 none(+nontemporal), 1 +Res(fp32), 2 relu^2, 3 RoPE(qkv).
template<int BN, int EPI, bool OUTBF, bool CONVB>
__global__ __launch_bounds__(256, 2) void k_mfma_gemm(const ushort* __restrict__ A,
                                                      const void* __restrict__ Wp,
                                                      void* __restrict__ Cp,
                                                      const float* __restrict__ Res,
                                                      const float* __restrict__ cosT,
                                                      const float* __restrict__ sinT,
                                                      int M, int N, int K) {
    constexpr int BM = 128;
    constexpr int MI = 4;
    constexpr int NI = BN / 32;
    constexpr bool DBUF = (BN <= 128);
    constexpr int NB = DBUF ? 2 : 1;
    __shared__ ushort As[NB][BM][64];   // swizzled: chunk c of row r at byte ((c^(r&7))<<4)
    __shared__ ushort Bs[NB][BN][64];
    const int tid = threadIdx.x;
    const int wid = tid >> 6, lane = tid & 63;
    const int wr = wid >> 1, wc = wid & 1;
    const int r16 = lane & 15, kc = lane >> 4;
    const int rx = (r16 & 7) << 4;
    const int srow8 = tid >> 3;
    const int sdcp = tid & 7;

    const int nwg = gridDim.x * gridDim.y;
    int orig = blockIdx.y * gridDim.x + blockIdx.x;
    int swz = (nwg & 7) ? orig : ((orig & 7) * (nwg >> 3) + (orig >> 3));
    const size_t bm = (size_t)(swz % gridDim.x) * BM;
    const size_t bn = (size_t)(swz / gridDim.x) * BN;

    auto stage = [&](int buf, int k0) {
        #pragma unroll
        for (int i = 0; i < 4; i++) {
            const int row = i * 32 + srow8;
            const ushort* g = A + (bm + row) * (size_t)K + k0 + ((sdcp ^ (row & 7)) * 8);
            async_copy16(g, (char*)As + buf * (BM * 128) + (i * 256 + tid) * 16);
        }
        if constexpr (!CONVB) {
            const ushort* Wb = (const ushort*)Wp;
            #pragma unroll
            for (int i = 0; i < BN / 32; i++) {
                const int row = i * 32 + srow8;
                const ushort* g = Wb + (bn + row) * (size_t)K + k0 + ((sdcp ^ (row & 7)) * 8);
                async_copy16(g, (char*)Bs + buf * (BN * 128) + (i * 256 + tid) * 16);
            }
        } else {
            const float* Wf = (const float*)Wp;
            #pragma unroll
            for (int i = 0; i < BN / 32; i++) {
                const int row = i * 32 + srow8;
                const float* src = Wf + (bn + row) * (size_t)K + k0 + sdcp * 8;
                float4 v0 = *(const float4*)(src);
                float4 v1 = *(const float4*)(src + 4);
                union { ushort u[8]; bf16x8 v; } tmp;
                tmp.u[0] = f2bf(v0.x); tmp.u[1] = f2bf(v0.y);
                tmp.u[2] = f2bf(v0.z); tmp.u[3] = f2bf(v0.w);
                tmp.u[4] = f2bf(v1.x); tmp.u[5] = f2bf(v1.y);
                tmp.u[6] = f2bf(v1.z); tmp.u[7] = f2bf(v1.w);
                *(bf16x8*)((char*)Bs + buf * (BN * 128) + row * 128 + ((sdcp ^ (row & 7)) << 4)) = tmp.v;
            }
        }
    };

    f32x4 acc[MI][NI];
    #pragma unroll
    for (int mi = 0; mi < MI; mi++)
        #pragma unroll
        for (int ni = 0; ni < NI; ni++) {
            f32x4 z = {0.f, 0.f, 0.f, 0.f};
            acc[mi][ni] = z;
        }

    auto compute = [&](int buf) {
        #pragma unroll
        for (int kk = 0; kk < 2; kk++) {
            bf16x8 af[MI], bfr[NI];
            #pragma unroll
            for (int mi = 0; mi < MI; mi++)
                af[mi] = *(const bf16x8*)((const char*)As + buf * (BM * 128) +
                                          (wr * 64 + mi * 16 + r16) * 128 +
                                          ((kk * 64 + kc * 16) ^ rx));
            #pragma unroll
            for (int ni = 0; ni < NI; ni++)
                bfr[ni] = *(const bf16x8*)((const char*)Bs + buf * (BN * 128) +
                                           (wc * (BN / 2) + ni * 16 + r16) * 128 +
                                           ((kk * 64 + kc * 16) ^ rx));
            #pragma unroll
            for (int mi = 0; mi < MI; mi++)
                #pragma unroll
                for (int ni = 0; ni < NI; ni++)
                    acc[mi][ni] = __builtin_amdgcn_mfma_f32_16x16x32_bf16(af[mi], bfr[ni],
                                                                          acc[mi][ni], 0, 0, 0);
        }
    };

    const int KSTEPS = K >> 6;
    if constexpr (DBUF) {
        stage(0, 0);
        __syncthreads();
        for (int step = 0; step < KSTEPS; ++step) {
            const int cur = step & 1;
            if (step + 1 < KSTEPS) stage(cur ^ 1, (step + 1) << 6);
            compute(cur);
            __syncthreads();
        }
    } else {
        for (int step = 0; step < KSTEPS; ++step) {
            stage(0, step << 6);
            __syncthreads();
            compute(0);
            __syncthreads();
        }
    }

    #pragma unroll
    for (int mi = 0; mi < MI; mi++) {
        #pragma unroll
        for (int j = 0; j < 4; j++) {
            const size_t row = bm + wr * 64 + mi * 16 + (lane >> 4) * 4 + j;
            if constexpr (EPI == 3) {
                static_assert(BN == 128, "rope epilogue assumes BN=128");
                const int sec = (int)((bn + wc * 64) >> 10);   // 0=q,1=k,2=v
                if (sec < 2) {
                    const int t = (int)(row & (T_ - 1));
                    #pragma unroll
                    for (int np = 0; np < 2; np++) {
                        const int i1 = np * 16 + r16;          // 0..31
                        float c = cosT[t * 32 + i1], s = sinT[t * 32 + i1];
                        float x1 = acc[mi][np][j], x2 = acc[mi][np + 2][j];
                        acc[mi][np][j]     = c * x1 - s * x2;
                        acc[mi][np + 2][j] = s * x1 + c * x2;
                    }
                }
            }
            #pragma unroll
            for (int ni = 0; ni < NI; ni++) {
                const size_t col = bn + wc * (BN / 2) + ni * 16 + r16;
                float v = acc[mi][ni][j];
                if constexpr (EPI == 1) v += Res[row * N + col];
                if constexpr (EPI == 2) { v = fmaxf(v, 0.f); v *= v; }
                if constexpr (OUTBF) {
                    ((ushort*)Cp)[row * N + col] = f2bf(v);
                } else if constexpr (EPI == 0) {
                    __builtin_nontemporal_store(v, (float*)Cp + row * N + col);
                } else {
                    ((float*)Cp)[row * N + col] = v;
                }
            }
        }
    }
}

// ---------------- 8-wave paired flash attention, KVBLK=128 ----------------
// Block = q-tiles (ip, 15-ip) of one (b,h). 512 threads: waves 0-3 -> hi tile,
// waves 4-7 -> lo tile, processed CONCURRENTLY per 128-key chunk (staged once,
// shared). Serial chunks = ceil((16-ip)/2) <= 8 (vs 17 units in the 4-wave pair),
// 2 waves/SIMD for latency hiding. Per-wave math identical to the verified
// KVBLK=128 kernel (R6).
__global__ __launch_bounds__(512) void k_attn_p8(const ushort* __restrict__ qkv,
                                                 ushort* __restrict__ ctx) {
    __shared__ __align__(16) char lds[65536];
    // [0,16K): K[128key][64d] swz (128B rows)
    // [16K,32K): Vt[64d][128key] swz (256B rows)
    // [32K,48K): hi Q (128B rows) then P (256B rows) | [48K,64K): lo Q/P
    const int tid = threadIdx.x;
    const int w = tid >> 6, lane = tid & 63;
    const int r16 = lane & 15, kc = lane >> 4;
    const int rx = (r16 & 7) << 4;
    const int ip = blockIdx.x;                 // 0..7
    const int tw = w >> 2;                     // 0 = hi tile, 1 = lo tile
    const int wq = w & 3;                      // row quarter within tile
    const int hib = (15 - ip) * 64, lob = ip * 64;
    const int tb = tw ? lob : hib;             // this wave's tile base
    const int pq = 32768 + tw * 16384;         // this wave's Q/P region
    const int bh = blockIdx.y, b = bh >> 4, h = bh & 15;
    const size_t tok0 = (size_t)b * T_;
    const ushort* kg = qkv + tok0 * (3 * D_) + D_ + h * DH_;
    const ushort* vg = qkv + tok0 * (3 * D_) + 2 * D_ + h * DH_;
    const float SCALE_LOG2E = 0.125f * 1.44269504089f;

    // stage both Q tiles (512 slots each; swizzled source, linear LDS dest)
    {
        const int bases[2] = { hib, lob };
        #pragma unroll
        for (int t = 0; t < 2; t++) {
            const int row = tid >> 3, dcp = tid & 7;
            const int d0 = (dcp ^ (row & 7)) * 8;
            const ushort* qg = qkv + (tok0 + bases[t] + row) * (3 * D_) + h * DH_ + d0;
            async_copy16(qg, lds + 32768 + t * 16384 + tid * 16);
        }
    }
    __syncthreads();
    bf16x8 aq[2];
    #pragma unroll
    for (int ks = 0; ks < 2; ks++) {
        const int row = wq * 16 + r16;
        aq[ks] = *(const bf16x8*)(lds + pq + row * 128 + ((ks * 64 + kc * 16) ^ rx));
    }

    f32x4 o[4];
    float m[4], l[4], corr[4];
    #pragma unroll
    for (int nd = 0; nd < 4; nd++) { f32x4 z = {0.f, 0.f, 0.f, 0.f}; o[nd] = z; }
    #pragma unroll
    for (int j = 0; j < 4; j++) { m[j] = -1e30f; l[j] = 0.f; }

    const int nchunks = (17 - ip) >> 1;        // ceil((16-ip)/2)
    for (int ch = 0; ch < nchunks; ch++) {
        const int kb = ch << 7;
        __syncthreads();                       // prev chunk fully consumed (incl aq on ch=0)
        // stage K: 128 rows x 64 d (1024 slots / 512 threads)
        #pragma unroll
        for (int i = 0; i < 2; i++) {
            const int slot = i * 512 + tid;
            const int row = slot >> 3, dcp = slot & 7;
            const int d0 = (dcp ^ (row & 7)) * 8;
            async_copy16(kg + (size_t)(kb + row) * (3 * D_) + d0, lds + slot * 16);
        }
        // stage Vt (transposed, reg-staged; 1 key x 16 d per thread)
        {
            const int key = tid >> 2, dbase = (tid & 3) * 16;
            const ushort* src = vg + (size_t)(kb + key) * (3 * D_) + dbase;
            bf16x8 v0 = *(const bf16x8*)(src);
            bf16x8 v1 = *(const bf16x8*)(src + 8);
            #pragma unroll
            for (int e = 0; e < 8; e++) {
                int d = dbase + e;
                *(ushort*)(lds + 16384 + d * 256 + ((key * 2) ^ ((d & 7) << 4))) = (ushort)v0[e];
                d = dbase + 8 + e;
                *(ushort*)(lds + 16384 + d * 256 + ((key * 2) ^ ((d & 7) << 4))) = (ushort)v1[e];
            }
        }
        __syncthreads();

        const bool active = (tw == 0) || (kb < lob + 64);   // wave-uniform
        if (active) {
            // S = Q K^T  (16 q-rows x 128 keys per wave)
            f32x4 s[8];
            #pragma unroll
            for (int ni = 0; ni < 8; ni++) { f32x4 z = {0.f, 0.f, 0.f, 0.f}; s[ni] = z; }
            __builtin_amdgcn_s_setprio(1);
            #pragma unroll
            for (int ks = 0; ks < 2; ks++)
                #pragma unroll
                for (int ni = 0; ni < 8; ni++) {
                    const int row = ni * 16 + r16;
                    bf16x8 kf = *(const bf16x8*)(lds + row * 128 + ((ks * 64 + kc * 16) ^ rx));
                    s[ni] = __builtin_amdgcn_mfma_f32_16x16x32_bf16(aq[ks], kf, s[ni], 0, 0, 0);
                }
            __builtin_amdgcn_s_setprio(0);

            const bool needmask = (kb + 127 > tb);
            #pragma unroll
            for (int j = 0; j < 4; j++) {
                const int qrow = tb + wq * 16 + kc * 4 + j;
                #pragma unroll
                for (int ni = 0; ni < 8; ni++) {
                    float v = s[ni][j] * SCALE_LOG2E;
                    if (needmask) { int key = kb + ni * 16 + r16; if (key > qrow) v = -1e30f; }
                    s[ni][j] = v;
                }
                float t0 = fmaxf(fmaxf(s[0][j], s[1][j]), fmaxf(s[2][j], s[3][j]));
                float t1 = fmaxf(fmaxf(s[4][j], s[5][j]), fmaxf(s[6][j], s[7][j]));
                float tmax = fmaxf(t0, t1);
                #pragma unroll
                for (int off = 1; off < 16; off <<= 1) tmax = fmaxf(tmax, __shfl_xor(tmax, off));
                const float mn = fmaxf(m[j], tmax);
                corr[j] = exp2f(m[j] - mn);
                m[j] = mn;
                float ps = 0.f;
                #pragma unroll
                for (int ni = 0; ni < 8; ni++) {
                    float p = exp2f(s[ni][j] - mn);
                    s[ni][j] = p;
                    ps += p;
                }
                #pragma unroll
                for (int off = 1; off < 16; off <<= 1) ps += __shfl_xor(ps, off);
                l[j] = l[j] * corr[j] + ps;
            }
            // P -> LDS bf16 (own wave's rows; 256B rows, swizzled)
            #pragma unroll
            for (int ni = 0; ni < 8; ni++)
                #pragma unroll
                for (int j = 0; j < 4; j++) {
                    const int row = wq * 16 + kc * 4 + j;
                    *(ushort*)(lds + pq + row * 256 + ((ni * 32 + r16 * 2) ^ ((row & 7) << 4))) = f2bf(s[ni][j]);
                }
            // rescale O
            #pragma unroll
            for (int nd = 0; nd < 4; nd++)
                #pragma unroll
                for (int j = 0; j < 4; j++) o[nd][j] *= corr[j];
            // O += P V  (K=128 over 4 ks slices)
            __builtin_amdgcn_s_setprio(1);
            #pragma unroll
            for (int ks = 0; ks < 4; ks++) {
                const int prow = wq * 16 + r16;
                bf16x8 pf = *(const bf16x8*)(lds + pq + prow * 256 + ((ks * 64 + kc * 16) ^ rx));
                #pragma unroll
                for (int nd = 0; nd < 4; nd++) {
                    const int drow = nd * 16 + r16;
                    bf16x8 vf = *(const bf16x8*)(lds + 16384 + drow * 256 + ((ks * 64 + kc * 16) ^ rx));
                    o[nd] = __builtin_amdgcn_mfma_f32_16x16x32_bf16(pf, vf, o[nd], 0, 0, 0);
                }
            }
            __builtin_amdgcn_s_setprio(0);
        }
    }

    // epilogue: each wave writes its 16 rows of its tile
    #pragma unroll
    for (int j = 0; j < 4; j++) {
        const float inv = 1.0f / l[j];
        const int row = tb + wq * 16 + kc * 4 + j;
        ushort* dst = ctx + (tok0 + row) * D_ + h * DH_;
        #pragma unroll
        for (int nd = 0; nd < 4; nd++)
            dst[nd * 16 + r16] = f2bf(o[nd][j] * inv);
    }
}

extern "C" void kernel_launch(void* const* d_in, const int* in_sizes, int n_in,
                              void* d_out, int out_size, void* d_ws, size_t ws_size,
                              hipStream_t stream) {
    const int*   xi   = (const int*)d_in[0];
    const float* emb  = (const float*)d_in[1];
    const float* Wqkv = (const float*)d_in[2];
    const float* Wout = (const float*)d_in[3];
    const float* W1   = (const float*)d_in[4];
    const float* W2   = (const float*)d_in[5];
    const float* lmh  = (const float*)d_in[6];
    float* out = (float*)d_out;

    const size_t NT = (size_t)B_ * T_;
    size_t off = 0;
    auto carve = [&](size_t bytes) -> char* {
        char* r = (char*)d_ws + off;
        off += (bytes + 255) & ~(size_t)255;
        return r;
    };
    float*  xbuf = (float*)carve(NT * D_ * 4);
    ushort* qkv  = (ushort*)carve(NT * 3 * D_ * 2);
    ushort* nb   = (ushort*)carve(NT * D_ * 2);
    ushort* ctxb = (ushort*)carve(NT * D_ * 2);
    ushort* hb   = (ushort*)carve(NT * 4 * D_ * 2);
    float*  cosT = (float*)carve(T_ * 32 * 4);
    float*  sinT = (float*)carve(T_ * 32 * 4);

    const size_t nWqkv = (size_t)L_ * 3 * D_ * D_;
    const size_t nWout = (size_t)L_ * D_ * D_;
    const size_t nW1   = (size_t)L_ * 4 * D_ * D_;
    const size_t nW2   = (size_t)L_ * 4 * D_ * D_;
    const size_t nLmh  = (size_t)V_ * D_;
    ushort* WqkvB = (ushort*)carve(nWqkv * 2);
    ushort* WoutB = (ushort*)carve(nWout * 2);
    ushort* W1B   = (ushort*)carve(nW1 * 2);
    ushort* W2B   = (ushort*)carve(nW2 * 2);
    ushort* lmhB  = (ushort*)carve(nLmh * 2);
    const bool preconv = (off <= ws_size);

    if (preconv) {
        k_cast<<<dim3(2048), dim3(256), 0, stream>>>((const float4*)Wqkv, (ushort4*)WqkvB, (int)(nWqkv / 4));
        k_cast<<<dim3(2048), dim3(256), 0, stream>>>((const float4*)Wout, (ushort4*)WoutB, (int)(nWout / 4));
        k_cast<<<dim3(2048), dim3(256), 0, stream>>>((const float4*)W1,   (ushort4*)W1B,   (int)(nW1 / 4));
        k_cast<<<dim3(2048), dim3(256), 0, stream>>>((const float4*)W2,   (ushort4*)W2B,   (int)(nW2 / 4));
        k_cast<<<dim3(2048), dim3(256), 0, stream>>>((const float4*)lmh,  (ushort4*)lmhB,  (int)(nLmh / 4));
    }

#define LAUNCH_GEMM(BN, EPI, OUTBF, GX, GY, Aq, Wb16, Wf32, Cq, Rq, Mv, Nv, Kv)              \
    do {                                                                                     \
        if (preconv)                                                                         \
            k_mfma_gemm<BN, EPI, OUTBF, false><<<dim3(GX, GY), dim3(256), 0, stream>>>(      \
                (const ushort*)(Aq), (const void*)(Wb16), (void*)(Cq), (Rq), cosT, sinT,     \
                Mv, Nv, Kv);                                                                 \
        else                                                                                 \
            k_mfma_gemm<BN, EPI, OUTBF, true><<<dim3(GX, GY), dim3(256), 0, stream>>>(       \
                (const ushort*)(Aq), (const void*)(Wf32), (void*)(Cq), (Rq), cosT, sinT,     \
                Mv, Nv, Kv);                                                                 \
    } while (0)

    k_rope_tables<<<dim3(T_), dim3(32), 0, stream>>>(cosT, sinT);
    k_gather<<<dim3(NT), dim3(256), 0, stream>>>(xi, emb, xbuf);

    for (int l = 0; l < L_; l++) {
        k_rmsnorm<<<dim3(NT), dim3(256), 0, stream>>>(xbuf, nb);
        LAUNCH_GEMM(128, 3, true, 16, 24, nb,
                    WqkvB + (size_t)l * 3 * D_ * D_, Wqkv + (size_t)l * 3 * D_ * D_,
                    qkv, nullptr, (int)NT, 3 * D_, D_);
        k_attn_p8<<<dim3(8, B_ * H_), dim3(512), 0, stream>>>(qkv, ctxb);
        LAUNCH_GEMM(64, 1, false, 16, 16, ctxb,
                    WoutB + (size_t)l * D_ * D_, Wout + (size_t)l * D_ * D_,
                    xbuf, xbuf, (int)NT, D_, D_);
        k_rmsnorm<<<dim3(NT), dim3(256), 0, stream>>>(xbuf, nb);
        LAUNCH_GEMM(128, 2, true, 16, 32, nb,
                    W1B + (size_t)l * 4 * D_ * D_, W1 + (size_t)l * 4 * D_ * D_,
                    hb, nullptr, (int)NT, 4 * D_, D_);
        LAUNCH_GEMM(64, 1, false, 16, 16, hb,
                    W2B + (size_t)l * 4 * D_ * D_, W2 + (size_t)l * 4 * D_ * D_,
                    xbuf, xbuf, (int)NT, D_, 4 * D_);
    }
    k_rmsnorm<<<dim3(NT), dim3(256), 0, stream>>>(xbuf, nb);
    LAUNCH_GEMM(256, 0, false, 16, 125, nb, lmhB, lmh, out, nullptr, (int)NT, V_, D_);
#undef LAUNCH_GEMM
}